// Round 2
// baseline (436.060 us; speedup 1.0000x reference)
//
#include <hip/hip_runtime.h>
#include <cstdint>
#include <cstddef>

typedef __bf16 bf16x8 __attribute__((ext_vector_type(8)));
typedef float f32x4 __attribute__((ext_vector_type(4)));

#define D_DIM 4096
#define NCOL 320
#define BM 64
#define NKT 128            // D_DIM / 32
#define EPS_F 1.1920929e-07f
#define HS 136             // padded Hg row stride (128 + 8)
#define ABUF 8192          // A tile: 64 rows x 32 k x 4B
#define BBUF 20480         // B tile: 320 n x 32 k x 2B
#define BUFS 28672         // ABUF + BBUF

// async global->LDS, 16B per lane; LDS dest is wave-uniform base + lane*16
__device__ __forceinline__ void gld16(const void* g, void* l) {
  __builtin_amdgcn_global_load_lds(
      (const __attribute__((address_space(1))) unsigned int*)g,
      (__attribute__((address_space(3))) unsigned int*)l,
      16, 0, 0);
}

// ---------------------------------------------------------------------------
// Pack: f32 weights -> bf16 Wp [kt][n][kk] (4096x320) and Qt [c2][n][k]
// (2x128x128). Wp row d: [dw1[d,0,:] | dw1[d,2,:] | dd[d,0:32] | dd[d,64:96]]
// ---------------------------------------------------------------------------
__global__ void dwp_pack(const float* __restrict__ dw1,
                         const float* __restrict__ qkw,
                         const float* __restrict__ dd,
                         __bf16* __restrict__ Wp,
                         __bf16* __restrict__ Qt) {
  const int tid = blockIdx.x * 256 + threadIdx.x;
  if (tid < 163840) {                 // 4096 d * 40 (n-blocks of 8)
    const int d = tid / 40;
    const int n = (tid % 40) * 8;
    const float* src;
    if (n < 128)       src = dw1 + (size_t)d * 512 + n;            // c=0
    else if (n < 256)  src = dw1 + (size_t)d * 512 + 128 + n;      // c=2: 256+(n-128)
    else if (n < 288)  src = dd  + (size_t)d * 128 + (n - 256);    // dd 0:32
    else               src = dd  + (size_t)d * 128 + (n - 224);    // dd 64:96
    f32x4 v0 = *(const f32x4*)src;
    f32x4 v1 = *(const f32x4*)(src + 4);
    const int base = (d >> 5) * 10240 + n * 32 + (d & 31);
#pragma unroll
    for (int q = 0; q < 4; ++q) {
      Wp[base + q * 32] = (__bf16)v0[q];
      Wp[base + (q + 4) * 32] = (__bf16)v1[q];
    }
  } else if (tid < 167936) {          // 2 * 128 * 16 Qt units
    const int q = tid - 163840;
    const int c2 = q >> 11;           // 0 -> c=0, 1 -> c=2
    const int rem = q & 2047;
    const int n = rem >> 4;           // i*32+m
    const int k0 = (rem & 15) * 8;
    const float* src = qkw + (size_t)c2 * 32768 + (size_t)k0 * 128 + n;
    bf16x8 v;
#pragma unroll
    for (int j = 0; j < 8; ++j) v[j] = (__bf16)src[(size_t)j * 128];
    *(bf16x8*)(Qt + (size_t)c2 * 16384 + (size_t)n * 128 + k0) = v;
  }
}

// ---------------------------------------------------------------------------
// Main fused kernel. Grid 256 x 512. Block tile: 64 rows x 320 cols.
// Wave w: rows (w&1)*32..+32, cols (w>>1)*80..+80 (5 col-tiles of 16).
// A tile staged as f32 with 16B-unit XOR swizzle (unit ^= row&7) to spread
// banks; converted to bf16 at fragment load. B tile pre-packed bf16.
// ---------------------------------------------------------------------------
__global__ __launch_bounds__(512, 2) void dwp_main(
    const float* __restrict__ X,
    const __bf16* __restrict__ Wp,
    const __bf16* __restrict__ Qt,
    const float* __restrict__ NS,
    float* __restrict__ Out) {
  __shared__ __align__(16) unsigned char lds[2 * BUFS];  // 57344 B
  const int t = threadIdx.x;
  const int w = t >> 6;
  const int l = t & 63;
  const int lq = l >> 4;
  const int lm = l & 15;
  const int m0 = blockIdx.x * BM;

  // A staging: lane t -> row t>>3, 16B-unit ((t&7) ^ (row&7))
  const float* gA = X + (size_t)(m0 + (t >> 3)) * D_DIM +
                    (size_t)(((t & 7) ^ ((t >> 3) & 7)) * 4);

  const int rbase = (w & 1) * 32;
  const int cbase = (w >> 1) * 80;

  // A fragment read offsets (two 16B units per frag, XOR-swizzled by lm&7)
  unsigned aoff0[2], aoff1[2], boff[5];
#pragma unroll
  for (int rt = 0; rt < 2; ++rt) {
    const int row = rbase + rt * 16 + lm;
    aoff0[rt] = (unsigned)(row * 128 + (((lq * 2 + 0) ^ (lm & 7)) * 16));
    aoff1[rt] = (unsigned)(row * 128 + (((lq * 2 + 1) ^ (lm & 7)) * 16));
  }
#pragma unroll
  for (int ct = 0; ct < 5; ++ct)
    boff[ct] = (unsigned)(ABUF + ((cbase + ct * 16 + lm) * 32 + lq * 8) * 2);

  f32x4 acc[2][5];
#pragma unroll
  for (int rt = 0; rt < 2; ++rt)
#pragma unroll
    for (int ct = 0; ct < 5; ++ct)
      acc[rt][ct] = (f32x4){0.f, 0.f, 0.f, 0.f};

  auto issue = [&](int kt, int buf) {
    unsigned char* base = lds + buf * BUFS;
    const __bf16* wsrc = Wp + (size_t)kt * 10240;
    gld16(gA + (size_t)kt * 32, base + w * 1024);                       // A (f32)
    gld16(wsrc + (size_t)t * 8, base + ABUF + w * 1024);                // B chunk0
    gld16(wsrc + (size_t)(4096 + t * 8), base + ABUF + 8192 + w * 1024);// B chunk1
    if (w < 4)
      gld16(wsrc + (size_t)(8192 + t * 8), base + ABUF + 16384 + w * 1024); // B chunk2
  };

  issue(0, 0);

  for (int kt = 0; kt < NKT; ++kt) {
    const int cur = kt & 1;
    __syncthreads();  // vmcnt(0) drain: tile kt landed; prev tile consumed
    if (kt + 1 < NKT) issue(kt + 1, cur ^ 1);
    const unsigned char* cb = lds + cur * BUFS;
    bf16x8 a[2], b[5];
#pragma unroll
    for (int rt = 0; rt < 2; ++rt) {
      f32x4 x0 = *(const f32x4*)(cb + aoff0[rt]);
      f32x4 x1 = *(const f32x4*)(cb + aoff1[rt]);
#pragma unroll
      for (int j = 0; j < 4; ++j) {
        a[rt][j] = (__bf16)x0[j];
        a[rt][4 + j] = (__bf16)x1[j];
      }
    }
#pragma unroll
    for (int ct = 0; ct < 5; ++ct) b[ct] = *(const bf16x8*)(cb + boff[ct]);
#pragma unroll
    for (int rt = 0; rt < 2; ++rt)
#pragma unroll
      for (int ct = 0; ct < 5; ++ct)
        acc[rt][ct] =
            __builtin_amdgcn_mfma_f32_16x16x32_bf16(a[rt], b[ct], acc[rt][ct], 0, 0, 0);
  }

  __syncthreads();  // all LDS reads done before Hg overwrite

  const float ns = NS[0];

  // E1: gelu(exact) -> Hg bf16 in LDS (cols<256); tanh -> Out (dd cols)
#pragma unroll
  for (int rt = 0; rt < 2; ++rt) {
#pragma unroll
    for (int ct = 0; ct < 5; ++ct) {
      const int ncol = cbase + ct * 16 + lm;
      const int rowb = rbase + rt * 16 + lq * 4;
      f32x4 v = acc[rt][ct];
      if (ncol < 256) {
        const int c2 = ncol >> 7;
        const int kcol = ncol & 127;
#pragma unroll
        for (int j = 0; j < 4; ++j) {
          float x = v[j];
          float g = 0.5f * x * (1.0f + erff(x * 0.70710678118f));
          *(__bf16*)(lds + (size_t)((c2 * 64 + rowb + j) * HS + kcol) * 2) = (__bf16)g;
        }
      } else {
        const int nd = ncol - 256;
        const int off = (nd < 32) ? (128 + nd) : (256 + nd);  // dd cols in Out
#pragma unroll
        for (int j = 0; j < 4; ++j)
          Out[(size_t)(m0 + rowb + j) * NCOL + off] = tanhf(v[j]);
      }
    }
  }
  __syncthreads();

  // E2: stage-2 GEMM  W2[row][c2,i*32+m] = sum_k Hg[c2][row][k] * Qt[c2][i*32+m][k]
  const int c2b = w >> 2;
  const int nnb = ((w >> 1) & 1) * 64;
  f32x4 acc2[2][4];
#pragma unroll
  for (int rt = 0; rt < 2; ++rt)
#pragma unroll
    for (int ct = 0; ct < 4; ++ct) acc2[rt][ct] = (f32x4){0.f, 0.f, 0.f, 0.f};

#pragma unroll
  for (int ks = 0; ks < 4; ++ks) {
    bf16x8 a2[2], b2[4];
#pragma unroll
    for (int rt = 0; rt < 2; ++rt)
      a2[rt] = *(const bf16x8*)(lds +
               (size_t)((c2b * 64 + rbase + rt * 16 + lm) * HS + ks * 32 + lq * 8) * 2);
#pragma unroll
    for (int ct = 0; ct < 4; ++ct)
      b2[ct] = *(const bf16x8*)(Qt + (size_t)c2b * 16384 +
               (size_t)(nnb + ct * 16 + lm) * 128 + ks * 32 + lq * 8);
#pragma unroll
    for (int rt = 0; rt < 2; ++rt)
#pragma unroll
      for (int ct = 0; ct < 4; ++ct)
        acc2[rt][ct] =
            __builtin_amdgcn_mfma_f32_16x16x32_bf16(a2[rt], b2[ct], acc2[rt][ct], 0, 0, 0);
  }

  // E3: RMS over 32 m (pairs of col-tiles), scale i>=2 by norm_scale, store f32
#pragma unroll
  for (int rt = 0; rt < 2; ++rt) {
#pragma unroll
    for (int p = 0; p < 2; ++p) {
      const int i = ((w >> 1) & 1) * 2 + p;
      const float sce = (i >= 2) ? ns : 1.0f;
      f32x4 va = acc2[rt][2 * p];
      f32x4 vb = acc2[rt][2 * p + 1];
#pragma unroll
      for (int j = 0; j < 4; ++j) {
        float s = va[j] * va[j] + vb[j] * vb[j];
        s += __shfl_xor(s, 1);
        s += __shfl_xor(s, 2);
        s += __shfl_xor(s, 4);
        s += __shfl_xor(s, 8);
        const float sc = rsqrtf(s * (1.0f / 32.0f) + EPS_F) * sce;
        const size_t row = (size_t)(m0 + rbase + rt * 16 + lq * 4 + j);
        const int off = c2b * 160 + i * 32;
        Out[row * NCOL + off + lm] = va[j] * sc;
        Out[row * NCOL + off + 16 + lm] = vb[j] * sc;
      }
    }
  }
}

extern "C" void kernel_launch(void* const* d_in, const int* in_sizes, int n_in,
                              void* d_out, int out_size, void* d_ws, size_t ws_size,
                              hipStream_t stream) {
  const float* qv  = (const float*)d_in[0];  // (4,4096,4096) f32
  const float* dw1 = (const float*)d_in[1];  // (4096,1,4,128) f32
  const float* qkw = (const float*)d_in[2];  // (1,4,128,4,32) f32
  const float* dd  = (const float*)d_in[3];  // (4096,1,128) f32
  const float* ns  = (const float*)d_in[4];  // (1,) f32
  float* out = (float*)d_out;

  __bf16* Wp = (__bf16*)d_ws;                 // 4096*320 bf16 = 2.62 MB
  __bf16* Qt = Wp + (size_t)4096 * 320;       // 2*128*128 bf16 = 64 KB

  dwp_pack<<<656, 256, 0, stream>>>(dw1, qkw, dd, Wp, Qt);
  dwp_main<<<256, 512, 0, stream>>>(qv, Wp, Qt, ns, out);
}

// Round 3
// 426.522 us; speedup vs baseline: 1.0224x; 1.0224x over previous
//
#include <hip/hip_runtime.h>
#include <cstdint>
#include <cstddef>

typedef __bf16 bf16x8 __attribute__((ext_vector_type(8)));
typedef float f32x4 __attribute__((ext_vector_type(4)));

#define D_DIM 4096
#define NCOL 320
#define BM 64
#define NKT 128            // D_DIM / 32
#define EPS_F 1.1920929e-07f
#define HS 136             // padded Hg row stride (128 + 8)
#define STG 28672          // ring stage: A 8KB f32 + B 20KB bf16
#define RING 4
#define SMEM (RING * STG)  // 114688 B dynamic LDS

// async global->LDS, 16B per lane; LDS dest is wave-uniform base + lane*16
__device__ __forceinline__ void gld16(const void* g, void* l) {
  __builtin_amdgcn_global_load_lds(
      (const __attribute__((address_space(1))) unsigned int*)g,
      (__attribute__((address_space(3))) unsigned int*)l,
      16, 0, 0);
}

// ---------------------------------------------------------------------------
// Pack: f32 weights -> bf16 Wp [kt][n][kk-swizzled] (coalesced via LDS
// transpose; 16B unit u of row n stored at slot u ^ ((n>>1)&3) to make the
// main kernel's B fragment ds_read_b128 2-way/free) and Qt [c2][n][k].
// Wp logical row d: [dw1[d,0,:] | dw1[d,2,:] | dd[d,0:32] | dd[d,64:96]]
// ---------------------------------------------------------------------------
__global__ void dwp_pack(const float* __restrict__ dw1,
                         const float* __restrict__ qkw,
                         const float* __restrict__ dd,
                         __bf16* __restrict__ Wp,
                         __bf16* __restrict__ Qt) {
  const int b = blockIdx.x;
  const int t = threadIdx.x;
  if (b < 128) {
    __shared__ __bf16 tile[10240];   // exact linear image of Wp[kt]
    const int kt = b;
    const int kk = t >> 3;           // 0..31
    const int d = kt * 32 + kk;
    const int u = kk >> 3;
#pragma unroll
    for (int j = 0; j < 5; ++j) {
      const int n0 = ((t & 7) + j * 8) * 8;
      const float* src;
      if (n0 < 128)      src = dw1 + (size_t)d * 512 + n0;          // c=0
      else if (n0 < 256) src = dw1 + (size_t)d * 512 + 128 + n0;    // c=2
      else if (n0 < 288) src = dd + (size_t)d * 128 + (n0 - 256);   // dd 0:32
      else               src = dd + (size_t)d * 128 + (n0 - 224);   // dd 64:96
      f32x4 v0 = *(const f32x4*)src;
      f32x4 v1 = *(const f32x4*)(src + 4);
#pragma unroll
      for (int q = 0; q < 8; ++q) {
        const int n = n0 + q;
        const int pos = n * 32 + ((u ^ ((n >> 1) & 3)) << 3) + (kk & 7);
        tile[pos] = (__bf16)((q < 4) ? v0[q] : v1[q - 4]);
      }
    }
    __syncthreads();
    __bf16* dst = Wp + (size_t)kt * 10240;
#pragma unroll
    for (int k = 0; k < 5; ++k) {
      const int u16 = t + k * 256;
      *(bf16x8*)(dst + u16 * 8) = *(const bf16x8*)(tile + u16 * 8);
    }
  } else {
    // Qt: 2*128*16 16B units, gather-transpose (tiny, L2-resident)
#pragma unroll
    for (int ii = 0; ii < 16; ++ii) {
      const int q = t + ii * 256;
      const int c2 = q >> 11;
      const int rem = q & 2047;
      const int n = rem >> 4;
      const int k0 = (rem & 15) * 8;
      const float* src = qkw + (size_t)c2 * 32768 + (size_t)k0 * 128 + n;
      bf16x8 v;
#pragma unroll
      for (int j = 0; j < 8; ++j) v[j] = (__bf16)src[(size_t)j * 128];
      *(bf16x8*)(Qt + (size_t)c2 * 16384 + (size_t)n * 128 + k0) = v;
    }
  }
}

// ---------------------------------------------------------------------------
// Main fused kernel. Grid 256 x 512. Block tile 64 rows x 320 cols.
// 4-stage LDS ring, raw s_barrier + manual s_waitcnt vmcnt(N): 3 stages of
// global_load_lds stay in flight across barriers (AITER-style pipeline).
// Per stage per wave: A(1) + B0(1) + B1(1) gld16, waves 0-3 also B2(1).
// ---------------------------------------------------------------------------
__global__ __launch_bounds__(512, 2) void dwp_main(
    const float* __restrict__ X,
    const __bf16* __restrict__ Wp,
    const __bf16* __restrict__ Qt,
    const float* __restrict__ NS,
    float* __restrict__ Out) {
  extern __shared__ __align__(16) unsigned char lds[];
  const int t = threadIdx.x;
  const int w = t >> 6;
  const int l = t & 63;
  const int lq = l >> 4;
  const int lm = l & 15;
  const int m0 = blockIdx.x * BM;

  // A staging: lane t -> row t>>3, 16B-unit ((t&7) ^ (row&7))
  const float* gA = X + (size_t)(m0 + (t >> 3)) * D_DIM +
                    (size_t)(((t & 7) ^ ((t >> 3) & 7)) * 4);

  const int rbase = (w & 1) * 32;
  const int cbase = (w >> 1) * 80;

  // A fragment offsets (unit XOR row&7); B offsets (unit XOR (n>>1)&3, baked
  // into Wp's global layout so staging stays linear)
  unsigned aoff0[2], aoff1[2], boff[5];
#pragma unroll
  for (int rt = 0; rt < 2; ++rt) {
    const int row = rbase + rt * 16 + lm;
    aoff0[rt] = (unsigned)(row * 128 + (((lq * 2 + 0) ^ (lm & 7)) * 16));
    aoff1[rt] = (unsigned)(row * 128 + (((lq * 2 + 1) ^ (lm & 7)) * 16));
  }
#pragma unroll
  for (int ct = 0; ct < 5; ++ct) {
    const int n = cbase + ct * 16 + lm;
    boff[ct] = (unsigned)(8192 + n * 64 + ((lq ^ ((n >> 1) & 3)) << 4));
  }

  f32x4 acc[2][5];
#pragma unroll
  for (int rt = 0; rt < 2; ++rt)
#pragma unroll
    for (int ct = 0; ct < 5; ++ct)
      acc[rt][ct] = (f32x4){0.f, 0.f, 0.f, 0.f};

  auto issue = [&](int kt) {
    unsigned char* base = lds + (kt & 3) * STG;
    const __bf16* wsrc = Wp + (size_t)kt * 10240;
    gld16(gA + (size_t)kt * 32, base + w * 1024);                        // A f32
    gld16(wsrc + (size_t)t * 8, base + 8192 + w * 1024);                 // B0
    gld16(wsrc + (size_t)(4096 + t * 8), base + 16384 + w * 1024);       // B1
    if (w < 4)
      gld16(wsrc + (size_t)(8192 + t * 8), base + 24576 + w * 1024);     // B2
  };

  auto body = [&](int kt) {
    const unsigned char* cb = lds + (kt & 3) * STG;
    bf16x8 a[2], b[5];
#pragma unroll
    for (int rt = 0; rt < 2; ++rt) {
      f32x4 x0 = *(const f32x4*)(cb + aoff0[rt]);
      f32x4 x1 = *(const f32x4*)(cb + aoff1[rt]);
#pragma unroll
      for (int j = 0; j < 4; ++j) {
        a[rt][j] = (__bf16)x0[j];
        a[rt][4 + j] = (__bf16)x1[j];
      }
    }
#pragma unroll
    for (int ct = 0; ct < 5; ++ct) b[ct] = *(const bf16x8*)(cb + boff[ct]);
#pragma unroll
    for (int rt = 0; rt < 2; ++rt)
#pragma unroll
      for (int ct = 0; ct < 5; ++ct)
        acc[rt][ct] =
            __builtin_amdgcn_mfma_f32_16x16x32_bf16(a[rt], b[ct], acc[rt][ct], 0, 0, 0);
  };

  issue(0);
  issue(1);
  issue(2);

  // Main loop: stage kt was issued 3 iterations ago; waves 0-3 have 4 ops/stage
  // in flight (12 outstanding -> vmcnt(8) drains stage kt), waves 4-7 have 3
  // (9 -> vmcnt(6)). Raw s_barrier: no compiler vmcnt(0) drain.
  for (int kt = 0; kt < NKT - 2; ++kt) {
    if (w < 4) asm volatile("s_waitcnt vmcnt(8) lgkmcnt(0)" ::: "memory");
    else       asm volatile("s_waitcnt vmcnt(6) lgkmcnt(0)" ::: "memory");
    asm volatile("s_barrier" ::: "memory");
    if (kt + 3 < NKT) issue(kt + 3);
    body(kt);
  }
  // peel kt = NKT-2: stages NKT-2, NKT-1 outstanding
  if (w < 4) asm volatile("s_waitcnt vmcnt(4) lgkmcnt(0)" ::: "memory");
  else       asm volatile("s_waitcnt vmcnt(3) lgkmcnt(0)" ::: "memory");
  asm volatile("s_barrier" ::: "memory");
  body(NKT - 2);
  // peel kt = NKT-1
  asm volatile("s_waitcnt vmcnt(0) lgkmcnt(0)" ::: "memory");
  asm volatile("s_barrier" ::: "memory");
  body(NKT - 1);

  __syncthreads();  // all ring reads done before Hg overwrite

  const float ns = NS[0];

  // E1: gelu(exact) -> Hg bf16 in LDS (cols<256); tanh -> Out (dd cols)
#pragma unroll
  for (int rt = 0; rt < 2; ++rt) {
#pragma unroll
    for (int ct = 0; ct < 5; ++ct) {
      const int ncol = cbase + ct * 16 + lm;
      const int rowb = rbase + rt * 16 + lq * 4;
      f32x4 v = acc[rt][ct];
      if (ncol < 256) {
        const int c2 = ncol >> 7;
        const int kcol = ncol & 127;
#pragma unroll
        for (int j = 0; j < 4; ++j) {
          float x = v[j];
          float g = 0.5f * x * (1.0f + erff(x * 0.70710678118f));
          *(__bf16*)(lds + (size_t)((c2 * 64 + rowb + j) * HS + kcol) * 2) = (__bf16)g;
        }
      } else {
        const int nd = ncol - 256;
        const int off = (nd < 32) ? (128 + nd) : (256 + nd);
#pragma unroll
        for (int j = 0; j < 4; ++j)
          Out[(size_t)(m0 + rowb + j) * NCOL + off] = tanhf(v[j]);
      }
    }
  }
  __syncthreads();

  // E2: stage-2 GEMM  W2[row][c2,i*32+m] = sum_k Hg[c2][row][k] * Qt[c2][i*32+m][k]
  const int c2b = w >> 2;
  const int nnb = ((w >> 1) & 1) * 64;
  f32x4 acc2[2][4];
#pragma unroll
  for (int rt = 0; rt < 2; ++rt)
#pragma unroll
    for (int ct = 0; ct < 4; ++ct) acc2[rt][ct] = (f32x4){0.f, 0.f, 0.f, 0.f};

#pragma unroll
  for (int ks = 0; ks < 4; ++ks) {
    bf16x8 a2[2], b2[4];
#pragma unroll
    for (int rt = 0; rt < 2; ++rt)
      a2[rt] = *(const bf16x8*)(lds +
               (size_t)((c2b * 64 + rbase + rt * 16 + lm) * HS + ks * 32 + lq * 8) * 2);
#pragma unroll
    for (int ct = 0; ct < 4; ++ct)
      b2[ct] = *(const bf16x8*)(Qt + (size_t)c2b * 16384 +
               (size_t)(nnb + ct * 16 + lm) * 128 + ks * 32 + lq * 8);
#pragma unroll
    for (int rt = 0; rt < 2; ++rt)
#pragma unroll
      for (int ct = 0; ct < 4; ++ct)
        acc2[rt][ct] =
            __builtin_amdgcn_mfma_f32_16x16x32_bf16(a2[rt], b2[ct], acc2[rt][ct], 0, 0, 0);
  }

  // E3: RMS over 32 m, scale i>=2 by norm_scale, store f32
#pragma unroll
  for (int rt = 0; rt < 2; ++rt) {
#pragma unroll
    for (int p = 0; p < 2; ++p) {
      const int i = ((w >> 1) & 1) * 2 + p;
      const float sce = (i >= 2) ? ns : 1.0f;
      f32x4 va = acc2[rt][2 * p];
      f32x4 vb = acc2[rt][2 * p + 1];
#pragma unroll
      for (int j = 0; j < 4; ++j) {
        float s = va[j] * va[j] + vb[j] * vb[j];
        s += __shfl_xor(s, 1);
        s += __shfl_xor(s, 2);
        s += __shfl_xor(s, 4);
        s += __shfl_xor(s, 8);
        const float sc = rsqrtf(s * (1.0f / 32.0f) + EPS_F) * sce;
        const size_t row = (size_t)(m0 + rbase + rt * 16 + lq * 4 + j);
        const int off = c2b * 160 + i * 32;
        Out[row * NCOL + off + lm] = va[j] * sc;
        Out[row * NCOL + off + 16 + lm] = vb[j] * sc;
      }
    }
  }
}

extern "C" void kernel_launch(void* const* d_in, const int* in_sizes, int n_in,
                              void* d_out, int out_size, void* d_ws, size_t ws_size,
                              hipStream_t stream) {
  const float* qv  = (const float*)d_in[0];  // (4,4096,4096) f32
  const float* dw1 = (const float*)d_in[1];  // (4096,1,4,128) f32
  const float* qkw = (const float*)d_in[2];  // (1,4,128,4,32) f32
  const float* dd  = (const float*)d_in[3];  // (4096,1,128) f32
  const float* ns  = (const float*)d_in[4];  // (1,) f32
  float* out = (float*)d_out;

  __bf16* Wp = (__bf16*)d_ws;                 // 4096*320 bf16 = 2.62 MB
  __bf16* Qt = Wp + (size_t)4096 * 320;       // 2*128*128 bf16 = 64 KB

  hipFuncSetAttribute((const void*)dwp_main,
                      hipFuncAttributeMaxDynamicSharedMemorySize, SMEM);

  dwp_pack<<<129, 256, 0, stream>>>(dw1, qkw, dd, Wp, Qt);
  dwp_main<<<256, 512, SMEM, stream>>>(qv, Wp, Qt, ns, out);
}

// Round 4
// 425.534 us; speedup vs baseline: 1.0247x; 1.0023x over previous
//
#include <hip/hip_runtime.h>
#include <cstdint>
#include <cstddef>

typedef __bf16 bf16x8 __attribute__((ext_vector_type(8)));
typedef float f32x4 __attribute__((ext_vector_type(4)));

#define D_DIM 4096
#define NCOL 320
#define BM 32              // rows per block
#define NKT 128            // D_DIM / 32
#define EPS_F 1.1920929e-07f
#define HS 136             // padded Hg row stride (128 + 8)
#define STG 24576          // ring stage: A 4KB f32 + B 20KB bf16
#define RING 3
#define SMEM (RING * STG)  // 73728 B dynamic LDS -> 2 blocks/CU

// async global->LDS, 16B per lane; LDS dest = wave-uniform base + lane*16
__device__ __forceinline__ void gld16(const void* g, void* l) {
  __builtin_amdgcn_global_load_lds(
      (const __attribute__((address_space(1))) unsigned int*)g,
      (__attribute__((address_space(3))) unsigned int*)l,
      16, 0, 0);
}

// ---------------------------------------------------------------------------
// Pack: f32 weights -> bf16 Wp [kt][n][kk-swizzled] (16B unit u of row n at
// slot u ^ ((n>>1)&3), so main-kernel B ds_read_b128 is 2-way/free) and
// Qt [c2][n][k]. Wp row d: [dw1[d,0,:] | dw1[d,2,:] | dd[d,0:32] | dd[d,64:96]]
// ---------------------------------------------------------------------------
__global__ void dwp_pack(const float* __restrict__ dw1,
                         const float* __restrict__ qkw,
                         const float* __restrict__ dd,
                         __bf16* __restrict__ Wp,
                         __bf16* __restrict__ Qt) {
  const int b = blockIdx.x;
  const int t = threadIdx.x;
  if (b < 128) {
    __shared__ __bf16 tile[10240];   // exact linear image of Wp[kt]
    const int kt = b;
    const int kk = t >> 3;           // 0..31
    const int d = kt * 32 + kk;
    const int u = kk >> 3;
#pragma unroll
    for (int j = 0; j < 5; ++j) {
      const int n0 = ((t & 7) + j * 8) * 8;
      const float* src;
      if (n0 < 128)      src = dw1 + (size_t)d * 512 + n0;          // c=0
      else if (n0 < 256) src = dw1 + (size_t)d * 512 + 128 + n0;    // c=2
      else if (n0 < 288) src = dd + (size_t)d * 128 + (n0 - 256);   // dd 0:32
      else               src = dd + (size_t)d * 128 + (n0 - 224);   // dd 64:96
      f32x4 v0 = *(const f32x4*)src;
      f32x4 v1 = *(const f32x4*)(src + 4);
#pragma unroll
      for (int q = 0; q < 8; ++q) {
        const int n = n0 + q;
        const int pos = n * 32 + ((u ^ ((n >> 1) & 3)) << 3) + (kk & 7);
        tile[pos] = (__bf16)((q < 4) ? v0[q] : v1[q - 4]);
      }
    }
    __syncthreads();
    __bf16* dst = Wp + (size_t)kt * 10240;
#pragma unroll
    for (int k = 0; k < 5; ++k) {
      const int u16 = t + k * 256;
      *(bf16x8*)(dst + u16 * 8) = *(const bf16x8*)(tile + u16 * 8);
    }
  } else {
    // Qt: 2*128*16 16B units, gather-transpose (tiny, L2-resident)
#pragma unroll
    for (int ii = 0; ii < 16; ++ii) {
      const int q = t + ii * 256;
      const int c2 = q >> 11;
      const int rem = q & 2047;
      const int n = rem >> 4;
      const int k0 = (rem & 15) * 8;
      const float* src = qkw + (size_t)c2 * 32768 + (size_t)k0 * 128 + n;
      bf16x8 v;
#pragma unroll
      for (int j = 0; j < 8; ++j) v[j] = (__bf16)src[(size_t)j * 128];
      *(bf16x8*)(Qt + (size_t)c2 * 16384 + (size_t)n * 128 + k0) = v;
    }
  }
}

// ---------------------------------------------------------------------------
// Main fused kernel. Grid 512 x 256 (BM=32 rows/block -> 2 blocks/CU).
// Ring-3 LDS: 2 stages always in flight (8 KB X/block, 16 KB/CU).
// Every thread stages symmetrically: 1 A-gld16 + 5 B-gld16 = 6 vmem/stage.
// Wave w (0-3): rows 0..31 (2 row-tiles), cols w*80..+80 (5 col-tiles).
// ---------------------------------------------------------------------------
__global__ __launch_bounds__(256, 2) void dwp_main(
    const float* __restrict__ X,
    const __bf16* __restrict__ Wp,
    const __bf16* __restrict__ Qt,
    const float* __restrict__ NS,
    float* __restrict__ Out) {
  extern __shared__ __align__(16) unsigned char lds[];
  const int t = threadIdx.x;
  const int w = t >> 6;
  const int l = t & 63;
  const int lq = l >> 4;
  const int lm = l & 15;
  const int m0 = blockIdx.x * BM;

  // A staging: thread t -> row t>>3 (0..31), 16B-unit ((t&7) ^ (row&7))
  const float* gA = X + (size_t)(m0 + (t >> 3)) * D_DIM +
                    (size_t)(((t & 7) ^ ((t >> 3) & 7)) * 4);

  const int cbase = w * 80;

  // fragment offsets: A f32 (unit XOR row&7), B bf16 (unit XOR (n>>1)&3,
  // baked into Wp's global layout so staging is linear)
  unsigned aoff0[2], aoff1[2], boff[5];
#pragma unroll
  for (int rt = 0; rt < 2; ++rt) {
    const int row = rt * 16 + lm;
    aoff0[rt] = (unsigned)(row * 128 + (((lq * 2 + 0) ^ (lm & 7)) * 16));
    aoff1[rt] = (unsigned)(row * 128 + (((lq * 2 + 1) ^ (lm & 7)) * 16));
  }
#pragma unroll
  for (int ct = 0; ct < 5; ++ct) {
    const int n = cbase + ct * 16 + lm;
    boff[ct] = (unsigned)(4096 + n * 64 + ((lq ^ ((n >> 1) & 3)) << 4));
  }

  f32x4 acc[2][5];
#pragma unroll
  for (int rt = 0; rt < 2; ++rt)
#pragma unroll
    for (int ct = 0; ct < 5; ++ct)
      acc[rt][ct] = (f32x4){0.f, 0.f, 0.f, 0.f};

  auto issue = [&](int kt, int slot) {
    unsigned char* base = lds + slot * STG;
    const __bf16* wsrc = Wp + (size_t)kt * 10240;
    gld16(gA + (size_t)kt * 32, base + w * 1024);                   // A f32 4KB
#pragma unroll
    for (int k = 0; k < 5; ++k)                                     // B 20KB
      gld16(wsrc + (size_t)(k * 2048) + t * 8,
            base + 4096 + k * 4096 + w * 1024);
  };

  auto body = [&](int kt, int slot) {
    const unsigned char* cb = lds + slot * STG;
    bf16x8 a[2], b[5];
#pragma unroll
    for (int rt = 0; rt < 2; ++rt) {
      f32x4 x0 = *(const f32x4*)(cb + aoff0[rt]);
      f32x4 x1 = *(const f32x4*)(cb + aoff1[rt]);
#pragma unroll
      for (int j = 0; j < 4; ++j) {
        a[rt][j] = (__bf16)x0[j];
        a[rt][4 + j] = (__bf16)x1[j];
      }
    }
#pragma unroll
    for (int ct = 0; ct < 5; ++ct) b[ct] = *(const bf16x8*)(cb + boff[ct]);
#pragma unroll
    for (int rt = 0; rt < 2; ++rt)
#pragma unroll
      for (int ct = 0; ct < 5; ++ct)
        acc[rt][ct] =
            __builtin_amdgcn_mfma_f32_16x16x32_bf16(a[rt], b[ct], acc[rt][ct], 0, 0, 0);
  };

  issue(0, 0);
  issue(1, 1);

  // Each wave has exactly 6 vmem ops per stage in flight; at the in-loop wait
  // stages kt,kt+1 are outstanding (12) -> vmcnt(6) drains stage kt. The wait
  // precedes s_barrier, so after the barrier stage kt is landed block-wide.
  int rb = 0;
  for (int kt = 0; kt < NKT - 1; ++kt) {
    asm volatile("s_waitcnt vmcnt(6)" ::: "memory");
    asm volatile("s_barrier" ::: "memory");
    if (kt + 2 < NKT) {
      int ri = rb + 2; if (ri >= RING) ri -= RING;
      issue(kt + 2, ri);
    }
    body(kt, rb);
    ++rb; if (rb == RING) rb = 0;
  }
  asm volatile("s_waitcnt vmcnt(0)" ::: "memory");
  asm volatile("s_barrier" ::: "memory");
  body(NKT - 1, rb);

  __syncthreads();  // all ring reads done before Hg overwrite

  const float ns = NS[0];

  // E1: gelu(exact) -> Hg bf16 in LDS (cols<256); tanh -> Out (dd cols)
#pragma unroll
  for (int rt = 0; rt < 2; ++rt) {
#pragma unroll
    for (int ct = 0; ct < 5; ++ct) {
      const int ncol = cbase + ct * 16 + lm;
      const int rowb = rt * 16 + lq * 4;
      f32x4 v = acc[rt][ct];
      if (ncol < 256) {
        const int c2 = ncol >> 7;
        const int kcol = ncol & 127;
#pragma unroll
        for (int j = 0; j < 4; ++j) {
          float x = v[j];
          float g = 0.5f * x * (1.0f + erff(x * 0.70710678118f));
          *(__bf16*)(lds + (size_t)((c2 * 32 + rowb + j) * HS + kcol) * 2) = (__bf16)g;
        }
      } else {
        const int nd = ncol - 256;
        const int off = (nd < 32) ? (128 + nd) : (256 + nd);
#pragma unroll
        for (int j = 0; j < 4; ++j)
          Out[(size_t)(m0 + rowb + j) * NCOL + off] = tanhf(v[j]);
      }
    }
  }
  __syncthreads();

  // E2: stage-2 GEMM  W2[row][c2,i*32+m] = sum_k Hg[c2][row][k]*Qt[c2][i*32+m][k]
  // wave w: c2 = w>>1, n-half = (w&1)*64
  const int c2b = w >> 1;
  const int nnb = (w & 1) * 64;
  f32x4 acc2[2][4];
#pragma unroll
  for (int rt = 0; rt < 2; ++rt)
#pragma unroll
    for (int ct = 0; ct < 4; ++ct) acc2[rt][ct] = (f32x4){0.f, 0.f, 0.f, 0.f};

#pragma unroll
  for (int ks = 0; ks < 4; ++ks) {
    bf16x8 a2[2], b2[4];
#pragma unroll
    for (int rt = 0; rt < 2; ++rt)
      a2[rt] = *(const bf16x8*)(lds +
               (size_t)((c2b * 32 + rt * 16 + lm) * HS + ks * 32 + lq * 8) * 2);
#pragma unroll
    for (int ct = 0; ct < 4; ++ct)
      b2[ct] = *(const bf16x8*)(Qt + (size_t)c2b * 16384 +
               (size_t)(nnb + ct * 16 + lm) * 128 + ks * 32 + lq * 8);
#pragma unroll
    for (int rt = 0; rt < 2; ++rt)
#pragma unroll
      for (int ct = 0; ct < 4; ++ct)
        acc2[rt][ct] =
            __builtin_amdgcn_mfma_f32_16x16x32_bf16(a2[rt], b2[ct], acc2[rt][ct], 0, 0, 0);
  }

  // E3: RMS over 32 m, scale i>=2 by norm_scale, store f32
#pragma unroll
  for (int rt = 0; rt < 2; ++rt) {
#pragma unroll
    for (int p = 0; p < 2; ++p) {
      const int i = (w & 1) * 2 + p;
      const float sce = (i >= 2) ? ns : 1.0f;
      f32x4 va = acc2[rt][2 * p];
      f32x4 vb = acc2[rt][2 * p + 1];
#pragma unroll
      for (int j = 0; j < 4; ++j) {
        float s = va[j] * va[j] + vb[j] * vb[j];
        s += __shfl_xor(s, 1);
        s += __shfl_xor(s, 2);
        s += __shfl_xor(s, 4);
        s += __shfl_xor(s, 8);
        const float sc = rsqrtf(s * (1.0f / 32.0f) + EPS_F) * sce;
        const size_t row = (size_t)(m0 + rt * 16 + lq * 4 + j);
        const int off = c2b * 160 + i * 32;
        Out[row * NCOL + off + lm] = va[j] * sc;
        Out[row * NCOL + off + 16 + lm] = vb[j] * sc;
      }
    }
  }
}

extern "C" void kernel_launch(void* const* d_in, const int* in_sizes, int n_in,
                              void* d_out, int out_size, void* d_ws, size_t ws_size,
                              hipStream_t stream) {
  const float* qv  = (const float*)d_in[0];  // (4,4096,4096) f32
  const float* dw1 = (const float*)d_in[1];  // (4096,1,4,128) f32
  const float* qkw = (const float*)d_in[2];  // (1,4,128,4,32) f32
  const float* dd  = (const float*)d_in[3];  // (4096,1,128) f32
  const float* ns  = (const float*)d_in[4];  // (1,) f32
  float* out = (float*)d_out;

  __bf16* Wp = (__bf16*)d_ws;                 // 4096*320 bf16 = 2.62 MB
  __bf16* Qt = Wp + (size_t)4096 * 320;       // 2*128*128 bf16 = 64 KB

  hipFuncSetAttribute((const void*)dwp_main,
                      hipFuncAttributeMaxDynamicSharedMemorySize, SMEM);

  dwp_pack<<<129, 256, 0, stream>>>(dw1, qkw, dd, Wp, Qt);
  dwp_main<<<512, 256, SMEM, stream>>>(qv, Wp, Qt, ns, out);
}